// Round 9
// baseline (245.382 us; speedup 1.0000x reference)
//
#include <hip/hip_runtime.h>
#include <math.h>

#define NUM_NODE 5000
#define BZ   64
#define SEQ  512
#define NBR  16
#define DIM  256
#define NCLS 20

#define ROWB  (DIM * 2)        // bf16 row bytes (512)
#define NCHUNK2 (SEQ / 4)      // 128 blocks per batch row (1 position per wave)
#define NCHUNK16 (SEQ / 16)    // fallback mapping
#define N4 (NUM_NODE * DIM / 4)

__device__ __forceinline__ int bcast_i(int v, int lane) {
    return __builtin_amdgcn_readlane(v, lane);
}
__device__ __forceinline__ float bcast_f(float v, int lane) {
    return __int_as_float(__builtin_amdgcn_readlane(__float_as_int(v), lane));
}
__device__ __forceinline__ unsigned bf16_rne(float f) {
    unsigned u = __float_as_uint(f);
    return (u + 0x7fffu + ((u >> 16) & 1u)) >> 16;
}
__device__ __forceinline__ float lo_bf16(unsigned u) { return __uint_as_float(u << 16); }
__device__ __forceinline__ float hi_bf16(unsigned u) { return __uint_as_float(u & 0xffff0000u); }

__global__ __launch_bounds__(256) void zero_ws_kernel(float* __restrict__ ws, int n) {
    int i = blockIdx.x * blockDim.x + threadIdx.x;
    if (i < n) ws[i] = 0.0f;
}

// fp32 (NUM_NODE,DIM) -> packed bf16 table; also zeroes the 64 KB accumulator.
__global__ __launch_bounds__(256) void cvt_emb_zero_kernel(
    const float4* __restrict__ src, uint2* __restrict__ dst, int n4,
    float* __restrict__ ypre, int nacc) {
    int i = blockIdx.x * blockDim.x + threadIdx.x;
    if (i < n4) {
        float4 v = src[i];
        uint2 o;
        o.x = bf16_rne(v.x) | (bf16_rne(v.y) << 16);
        o.y = bf16_rne(v.z) | (bf16_rne(v.w) << 16);
        dst[i] = o;
    }
    if (i < nacc) ypre[i] = 0.0f;
}

// One wave per (b,s) position. bs is forced wave-uniform via readfirstlane so
// the ENTIRE index/weight path (NX row, EW row, 16 edge_w gathers, X, node_w)
// compiles to scalar s_load (lgkmcnt) -> SGPRs. The vector pipe issues only
// the 9 row loads (uint4 16B/lane, two 512B bf16 rows per load via wave
// halves), whose consumption no longer waits behind the random edge_w HBM
// miss in the in-order vmcnt queue. No shfl broadcasts needed at all.
__global__ __launch_bounds__(256, 4) void gnn_gather_kernel(
    const int*   __restrict__ X,        // (BZ, SEQ)
    const int*   __restrict__ NX,       // (BZ, SEQ, NBR)
    const int*   __restrict__ EW,       // (BZ, SEQ, NBR)
    const char*  __restrict__ embb,     // (NUM_NODE, ROWB) packed bf16 table
    const float* __restrict__ edge_w,   // (EDGE_ROWS, 1)
    const float* __restrict__ node_w,   // (NUM_NODE, 1)
    float*       __restrict__ ypre)     // (BZ, DIM) atomic accumulator
{
    __shared__ float lds[4][DIM];

    const int b     = blockIdx.x / NCHUNK2;
    const int chunk = blockIdx.x % NCHUNK2;
    const int wave  = threadIdx.x >> 6;
    const int lane  = threadIdx.x & 63;
    const int half  = lane >> 5;
    const int sub   = lane & 31;
    const int voff  = sub * 16;          // byte offset within a bf16 row

    // wave-uniform position index -> scalar address paths
    const int bs = __builtin_amdgcn_readfirstlane(b * SEQ + chunk * 4 + wave);

    const int* __restrict__ NXp = NX + bs * NBR;
    const int* __restrict__ EWp = EW + bs * NBR;

    // scalar loads: neighbor ids and edge weights into SGPRs
    int   nid[NBR];
    float wgt[NBR];
    #pragma unroll
    for (int k = 0; k < NBR; ++k) nid[k] = NXp[k];
    #pragma unroll
    for (int k = 0; k < NBR; ++k) wgt[k] = edge_w[EWp[k]];

    const int   x  = X[bs];          // scalar
    const float nn = node_w[x];      // scalar

    // ---- issue all row loads back-to-back (8 dual-row + 1 self) ----
    uint4 e[8];
    #pragma unroll
    for (int j = 0; j < 8; ++j) {
        const int n = half ? nid[2 * j + 1] : nid[2 * j];
        e[j] = *(const uint4*)(embb + (size_t)n * ROWB + voff);
    }
    const uint4 es = *(const uint4*)(embb + (size_t)x * ROWB + voff);

    // ---- consume in issue order ----
    float m[8];
    #pragma unroll
    for (int i = 0; i < 8; ++i) m[i] = -INFINITY;

    #pragma unroll
    for (int j = 0; j < 8; ++j) {
        const float w = half ? wgt[2 * j + 1] : wgt[2 * j];
        m[0] = fmaxf(m[0], lo_bf16(e[j].x) * w);
        m[1] = fmaxf(m[1], hi_bf16(e[j].x) * w);
        m[2] = fmaxf(m[2], lo_bf16(e[j].y) * w);
        m[3] = fmaxf(m[3], hi_bf16(e[j].y) * w);
        m[4] = fmaxf(m[4], lo_bf16(e[j].z) * w);
        m[5] = fmaxf(m[5], hi_bf16(e[j].z) * w);
        m[6] = fmaxf(m[6], lo_bf16(e[j].w) * w);
        m[7] = fmaxf(m[7], hi_bf16(e[j].w) * w);
    }

    // combine the two half-wave neighbor subsets
    #pragma unroll
    for (int i = 0; i < 8; ++i)
        m[i] = fmaxf(m[i], __shfl_xor(m[i], 32));

    const float om = 1.0f - nn;
    float acc[8];
    acc[0] = om * m[0] + nn * lo_bf16(es.x);
    acc[1] = om * m[1] + nn * hi_bf16(es.x);
    acc[2] = om * m[2] + nn * lo_bf16(es.y);
    acc[3] = om * m[3] + nn * hi_bf16(es.y);
    acc[4] = om * m[4] + nn * lo_bf16(es.z);
    acc[5] = om * m[5] + nn * hi_bf16(es.z);
    acc[6] = om * m[6] + nn * lo_bf16(es.w);
    acc[7] = om * m[7] + nn * hi_bf16(es.w);

    if (half == 0) {
        *(float4*)&lds[wave][8 * sub]     = make_float4(acc[0], acc[1], acc[2], acc[3]);
        *(float4*)&lds[wave][8 * sub + 4] = make_float4(acc[4], acc[5], acc[6], acc[7]);
    }
    __syncthreads();

    const int t = threadIdx.x;   // 0..255 -> one dim each
    atomicAdd(&ypre[b * DIM + t], lds[0][t] + lds[1][t] + lds[2][t] + lds[3][t]);
}

// Fallback (tiny ws): fp32 gathers, atomic accumulation into (BZ,DIM).
__global__ __launch_bounds__(256) void gnn_gather_f32_kernel(
    const int*   __restrict__ X,
    const int*   __restrict__ NX,
    const int*   __restrict__ EW,
    const float* __restrict__ node_emb,
    const float* __restrict__ edge_w,
    const float* __restrict__ node_w,
    float*       __restrict__ dst)
{
    __shared__ float lds[4][DIM];
    const int b     = blockIdx.x / NCHUNK16;
    const int chunk = blockIdx.x % NCHUNK16;
    const int wave  = threadIdx.x >> 6;
    const int lane  = threadIdx.x & 63;
    const int s0  = chunk * 16 + wave * 4;
    const int bs0 = b * SEQ + s0;

    const int   nx  = NX[bs0 * NBR + lane];
    const float ew  = edge_w[EW[bs0 * NBR + lane]];
    int xv = 0; float nwv = 0.f;
    if (lane < 4) { xv = X[bs0 + lane]; nwv = node_w[xv]; }

    float4 acc = make_float4(0.f, 0.f, 0.f, 0.f);
    for (int p = 0; p < 4; ++p) {
        float4 m = make_float4(-INFINITY, -INFINITY, -INFINITY, -INFINITY);
        for (int k = 0; k < NBR; ++k) {
            const int   n = bcast_i(nx, p * 16 + k);
            const float w = bcast_f(ew, p * 16 + k);
            const float4 e = *(const float4*)(node_emb + (size_t)n * DIM + 4 * lane);
            m.x = fmaxf(m.x, e.x * w); m.y = fmaxf(m.y, e.y * w);
            m.z = fmaxf(m.z, e.z * w); m.w = fmaxf(m.w, e.w * w);
        }
        const int   x  = bcast_i(xv, p);
        const float nnv = bcast_f(nwv, p);
        const float om = 1.0f - nnv;
        const float4 r = *(const float4*)(node_emb + (size_t)x * DIM + 4 * lane);
        acc.x += om * m.x + nnv * r.x; acc.y += om * m.y + nnv * r.y;
        acc.z += om * m.z + nnv * r.z; acc.w += om * m.w + nnv * r.w;
    }
    *(float4*)&lds[wave][4 * lane] = acc;
    __syncthreads();
    const int t = threadIdx.x;
    atomicAdd(&dst[b * DIM + t], lds[0][t] + lds[1][t] + lds[2][t] + lds[3][t]);
}

// One block (256 threads) per batch row: GEMV(256->20) + bias + relu +
// log_softmax from the 64 KB accumulator.
__global__ __launch_bounds__(256) void gnn_head_kernel(
    const float* __restrict__ ypre,
    const float* __restrict__ fc_W,
    const float* __restrict__ fc_b,
    float*       __restrict__ out)
{
    __shared__ float vals[NCLS];
    __shared__ float lse;

    const int b = blockIdx.x;
    const int t = threadIdx.x;
    const int wave = t >> 6;
    const int lane = t & 63;

    const float4 y4 = *(const float4*)(ypre + b * DIM + 4 * lane);

    #pragma unroll
    for (int ci = 0; ci < 5; ++ci) {
        const int c = wave * 5 + ci;
        const float4 w4 = *(const float4*)(fc_W + c * DIM + 4 * lane);
        float d = y4.x * w4.x + y4.y * w4.y + y4.z * w4.z + y4.w * w4.w;
        #pragma unroll
        for (int off = 32; off; off >>= 1) d += __shfl_xor(d, off);
        if (lane == 0) vals[c] = fmaxf(d + fc_b[c], 0.0f);
    }
    __syncthreads();

    if (t == 0) {
        float mx = -INFINITY;
        for (int c = 0; c < NCLS; ++c) mx = fmaxf(mx, vals[c]);
        float s = 0.0f;
        for (int c = 0; c < NCLS; ++c) s += expf(vals[c] - mx);
        lse = mx + logf(s);
    }
    __syncthreads();

    if (t < NCLS) out[b * NCLS + t] = vals[t] - lse;
}

extern "C" void kernel_launch(void* const* d_in, const int* in_sizes, int n_in,
                              void* d_out, int out_size, void* d_ws, size_t ws_size,
                              hipStream_t stream) {
    const int*   X        = (const int*)  d_in[0];
    const int*   NX       = (const int*)  d_in[1];
    const int*   EW       = (const int*)  d_in[2];
    const float* node_emb = (const float*)d_in[3];
    const float* edge_w   = (const float*)d_in[4];
    const float* node_w   = (const float*)d_in[5];
    const float* fc_W     = (const float*)d_in[6];
    const float* fc_b     = (const float*)d_in[7];
    float* out = (float*)d_out;

    const size_t acc_bytes = (size_t)BZ * DIM * sizeof(float);                 // 64 KB
    const size_t emb_bytes = (size_t)NUM_NODE * DIM * sizeof(unsigned short);  // 2.56 MB
    float* ypre = (float*)d_ws;
    char*  embb = (char*)d_ws + acc_bytes;

    if (ws_size >= acc_bytes + emb_bytes) {
        cvt_emb_zero_kernel<<<(N4 + 255) / 256, 256, 0, stream>>>(
            (const float4*)node_emb, (uint2*)embb, N4, ypre, BZ * DIM);
        gnn_gather_kernel<<<BZ * NCHUNK2, 256, 0, stream>>>(
            X, NX, EW, embb, edge_w, node_w, ypre);
        gnn_head_kernel<<<BZ, 256, 0, stream>>>(ypre, fc_W, fc_b, out);
    } else {
        zero_ws_kernel<<<(BZ * DIM + 255) / 256, 256, 0, stream>>>(ypre, BZ * DIM);
        gnn_gather_f32_kernel<<<BZ * NCHUNK16, 256, 0, stream>>>(
            X, NX, EW, node_emb, edge_w, node_w, ypre);
        gnn_head_kernel<<<BZ, 256, 0, stream>>>(ypre, fc_W, fc_b, out);
    }
}

// Round 10
// 177.830 us; speedup vs baseline: 1.3799x; 1.3799x over previous
//
#include <hip/hip_runtime.h>
#include <math.h>

#define NUM_NODE 5000
#define BZ   64
#define SEQ  512
#define NBR  16
#define DIM  256
#define NCLS 20

#define ROWB  (DIM * 2)        // bf16 row bytes (512)
#define NCHUNK2 (SEQ / 4)      // 128 blocks per batch row (1 position per wave)
#define NCHUNK16 (SEQ / 16)    // fallback mapping

__device__ __forceinline__ int bcast_i(int v, int lane) {
    return __builtin_amdgcn_readlane(v, lane);   // uniform (SGPR) result
}
__device__ __forceinline__ float bcast_f(float v, int lane) {
    return __int_as_float(__builtin_amdgcn_readlane(__float_as_int(v), lane));
}
__device__ __forceinline__ unsigned bf16_rne(float f) {
    unsigned u = __float_as_uint(f);
    return (u + 0x7fffu + ((u >> 16) & 1u)) >> 16;
}
__device__ __forceinline__ float lo_bf16(unsigned u) { return __uint_as_float(u << 16); }
__device__ __forceinline__ float hi_bf16(unsigned u) { return __uint_as_float(u & 0xffff0000u); }

__global__ __launch_bounds__(256) void zero_ws_kernel(float* __restrict__ ws, int n) {
    int i = blockIdx.x * blockDim.x + threadIdx.x;
    if (i < n) ws[i] = 0.0f;
}

// fp32 (NUM_NODE,DIM) -> packed bf16 table; also zero-inits the 64 KB
// (BZ,DIM) accumulator (first 16384 threads) to save a launch.
__global__ __launch_bounds__(256) void cvt_emb_zero_kernel(
    const float4* __restrict__ src, uint2* __restrict__ dst, int n4,
    float* __restrict__ ypre, int nacc) {
    int i = blockIdx.x * blockDim.x + threadIdx.x;
    if (i < n4) {
        float4 v = src[i];
        uint2 o;
        o.x = bf16_rne(v.x) | (bf16_rne(v.y) << 16);
        o.y = bf16_rne(v.z) | (bf16_rne(v.w) << 16);
        dst[i] = o;
    }
    if (i < nacc) ypre[i] = 0.0f;
}

// One wave per (b,s) position. A 16B/lane uint4 load covers TWO 512B bf16
// rows (lanes 0-31 -> neighbor 2j, lanes 32-63 -> neighbor 2j+1): whole
// neighborhood = 8 loads, issued back-to-back before consumption. Block
// result goes straight into the 64 KB (BZ,DIM) accumulator via atomicAdd
// (128 adds/address -> negligible contention). In-kernel edge_w gather
// overlaps with row loads (R7 showed splitting it out serializes; R9 showed
// scalarizing it spills). 8 waves/SIMD for latency hiding.
__global__ __launch_bounds__(256, 8) void gnn_gather_kernel(
    const int*   __restrict__ X,        // (BZ, SEQ)
    const int*   __restrict__ NX,       // (BZ, SEQ, NBR)
    const int*   __restrict__ EW,       // (BZ, SEQ, NBR)
    const char*  __restrict__ embb,     // (NUM_NODE, ROWB) packed bf16 table
    const float* __restrict__ edge_w,   // (EDGE_ROWS, 1)
    const float* __restrict__ node_w,   // (NUM_NODE, 1)
    float*       __restrict__ ypre)     // (BZ, DIM) atomic accumulator
{
    __shared__ float lds[4][DIM];

    const int b     = blockIdx.x / NCHUNK2;
    const int chunk = blockIdx.x % NCHUNK2;
    const int wave  = threadIdx.x >> 6;
    const int lane  = threadIdx.x & 63;
    const int half  = lane >> 5;
    const int sub   = lane & 31;
    const int voff  = sub * 16;          // byte offset within a bf16 row

    const int s  = chunk * 4 + wave;
    const int bs = b * SEQ + s;

    // 16 lanes fetch this position's neighbor ids / edge-weight indices
    int   nxv = 0;
    float ewv = 0.f;
    if (lane < NBR) {
        nxv = __builtin_nontemporal_load(&NX[bs * NBR + lane]);
        const int ewi = __builtin_nontemporal_load(&EW[bs * NBR + lane]);
        ewv = __builtin_nontemporal_load(&edge_w[ewi]);
    }
    const int   x  = X[bs];        // wave-uniform address -> broadcast line
    const float nn = node_w[x];

    // ---- issue ALL gather loads back-to-back ----
    uint4 e[8];
    #pragma unroll
    for (int j = 0; j < 8; ++j) {
        const int n0 = bcast_i(nxv, 2 * j);
        const int n1 = bcast_i(nxv, 2 * j + 1);
        const int n  = half ? n1 : n0;
        e[j] = *(const uint4*)(embb + (size_t)n * ROWB + voff);
    }
    const uint4 es = *(const uint4*)(embb + (size_t)x * ROWB + voff); // self row

    // ---- consume in issue order (decreasing vmcnt) ----
    float m[8];
    #pragma unroll
    for (int i = 0; i < 8; ++i) m[i] = -INFINITY;

    #pragma unroll
    for (int j = 0; j < 8; ++j) {
        const float w0 = bcast_f(ewv, 2 * j);
        const float w1 = bcast_f(ewv, 2 * j + 1);
        const float w  = half ? w1 : w0;
        m[0] = fmaxf(m[0], lo_bf16(e[j].x) * w);
        m[1] = fmaxf(m[1], hi_bf16(e[j].x) * w);
        m[2] = fmaxf(m[2], lo_bf16(e[j].y) * w);
        m[3] = fmaxf(m[3], hi_bf16(e[j].y) * w);
        m[4] = fmaxf(m[4], lo_bf16(e[j].z) * w);
        m[5] = fmaxf(m[5], hi_bf16(e[j].z) * w);
        m[6] = fmaxf(m[6], lo_bf16(e[j].w) * w);
        m[7] = fmaxf(m[7], hi_bf16(e[j].w) * w);
    }

    // combine the two half-wave neighbor subsets
    #pragma unroll
    for (int i = 0; i < 8; ++i)
        m[i] = fmaxf(m[i], __shfl_xor(m[i], 32));

    const float om = 1.0f - nn;
    float acc[8];
    acc[0] = om * m[0] + nn * lo_bf16(es.x);
    acc[1] = om * m[1] + nn * hi_bf16(es.x);
    acc[2] = om * m[2] + nn * lo_bf16(es.y);
    acc[3] = om * m[3] + nn * hi_bf16(es.y);
    acc[4] = om * m[4] + nn * lo_bf16(es.z);
    acc[5] = om * m[5] + nn * hi_bf16(es.z);
    acc[6] = om * m[6] + nn * lo_bf16(es.w);
    acc[7] = om * m[7] + nn * hi_bf16(es.w);

    if (half == 0) {
        *(float4*)&lds[wave][8 * sub]     = make_float4(acc[0], acc[1], acc[2], acc[3]);
        *(float4*)&lds[wave][8 * sub + 4] = make_float4(acc[4], acc[5], acc[6], acc[7]);
    }
    __syncthreads();

    const int t = threadIdx.x;   // 0..255 -> one dim each
    atomicAdd(&ypre[b * DIM + t], lds[0][t] + lds[1][t] + lds[2][t] + lds[3][t]);
}

// Fallback (tiny ws): fp32 gathers, atomic accumulation into (BZ,DIM).
__global__ __launch_bounds__(256) void gnn_gather_f32_kernel(
    const int*   __restrict__ X,
    const int*   __restrict__ NX,
    const int*   __restrict__ EW,
    const float* __restrict__ node_emb,
    const float* __restrict__ edge_w,
    const float* __restrict__ node_w,
    float*       __restrict__ dst)      // (BZ, DIM) atomic
{
    __shared__ float lds[4][DIM];
    const int b     = blockIdx.x / NCHUNK16;
    const int chunk = blockIdx.x % NCHUNK16;
    const int wave  = threadIdx.x >> 6;
    const int lane  = threadIdx.x & 63;
    const int s0  = chunk * 16 + wave * 4;
    const int bs0 = b * SEQ + s0;

    const int   nx  = NX[bs0 * NBR + lane];
    const float ew  = edge_w[EW[bs0 * NBR + lane]];
    int xv = 0; float nwv = 0.f;
    if (lane < 4) { xv = X[bs0 + lane]; nwv = node_w[xv]; }

    float4 acc = make_float4(0.f, 0.f, 0.f, 0.f);
    for (int p = 0; p < 4; ++p) {
        float4 m = make_float4(-INFINITY, -INFINITY, -INFINITY, -INFINITY);
        for (int k = 0; k < NBR; ++k) {
            const int   n = bcast_i(nx, p * 16 + k);
            const float w = bcast_f(ew, p * 16 + k);
            const float4 e = *(const float4*)(node_emb + (size_t)n * DIM + 4 * lane);
            m.x = fmaxf(m.x, e.x * w); m.y = fmaxf(m.y, e.y * w);
            m.z = fmaxf(m.z, e.z * w); m.w = fmaxf(m.w, e.w * w);
        }
        const int   x  = bcast_i(xv, p);
        const float nn = bcast_f(nwv, p);
        const float om = 1.0f - nn;
        const float4 r = *(const float4*)(node_emb + (size_t)x * DIM + 4 * lane);
        acc.x += om * m.x + nn * r.x; acc.y += om * m.y + nn * r.y;
        acc.z += om * m.z + nn * r.z; acc.w += om * m.w + nn * r.w;
    }
    *(float4*)&lds[wave][4 * lane] = acc;
    __syncthreads();
    const int t = threadIdx.x;
    atomicAdd(&dst[b * DIM + t], lds[0][t] + lds[1][t] + lds[2][t] + lds[3][t]);
}

// One block (256 threads) per batch row: GEMV(256->20) + bias + relu +
// log_softmax from the 64 KB accumulator.
__global__ __launch_bounds__(256) void gnn_head_kernel(
    const float* __restrict__ ypre,  // (BZ, DIM)
    const float* __restrict__ fc_W,  // (NCLS, DIM)
    const float* __restrict__ fc_b,  // (NCLS,)
    float*       __restrict__ out)   // (BZ, NCLS)
{
    __shared__ float vals[NCLS];
    __shared__ float lse;

    const int b = blockIdx.x;
    const int t = threadIdx.x;
    const int wave = t >> 6;
    const int lane = t & 63;

    const float4 y4 = *(const float4*)(ypre + b * DIM + 4 * lane);

    #pragma unroll
    for (int ci = 0; ci < 5; ++ci) {
        const int c = wave * 5 + ci;           // 4 waves x 5 classes = 20
        const float4 w4 = *(const float4*)(fc_W + c * DIM + 4 * lane);
        float d = y4.x * w4.x + y4.y * w4.y + y4.z * w4.z + y4.w * w4.w;
        #pragma unroll
        for (int off = 32; off; off >>= 1) d += __shfl_xor(d, off);
        if (lane == 0) vals[c] = fmaxf(d + fc_b[c], 0.0f);
    }
    __syncthreads();

    if (t == 0) {
        float mx = -INFINITY;
        for (int c = 0; c < NCLS; ++c) mx = fmaxf(mx, vals[c]);
        float s = 0.0f;
        for (int c = 0; c < NCLS; ++c) s += expf(vals[c] - mx);
        lse = mx + logf(s);
    }
    __syncthreads();

    if (t < NCLS) out[b * NCLS + t] = vals[t] - lse;
}

extern "C" void kernel_launch(void* const* d_in, const int* in_sizes, int n_in,
                              void* d_out, int out_size, void* d_ws, size_t ws_size,
                              hipStream_t stream) {
    const int*   X        = (const int*)  d_in[0];
    const int*   NX       = (const int*)  d_in[1];
    const int*   EW       = (const int*)  d_in[2];
    const float* node_emb = (const float*)d_in[3];
    const float* edge_w   = (const float*)d_in[4];
    const float* node_w   = (const float*)d_in[5];
    const float* fc_W     = (const float*)d_in[6];
    const float* fc_b     = (const float*)d_in[7];
    float* out = (float*)d_out;

    const size_t acc_bytes = (size_t)BZ * DIM * sizeof(float);                 // 64 KB
    const size_t emb_bytes = (size_t)NUM_NODE * DIM * sizeof(unsigned short);  // 2.56 MB
    float* ypre = (float*)d_ws;
    char*  embb = (char*)d_ws + acc_bytes;

    if (ws_size >= acc_bytes + emb_bytes) {
        const int n4 = NUM_NODE * DIM / 4;   // 320000
        cvt_emb_zero_kernel<<<(n4 + 255) / 256, 256, 0, stream>>>(
            (const float4*)node_emb, (uint2*)embb, n4, ypre, BZ * DIM);
        gnn_gather_kernel<<<BZ * NCHUNK2, 256, 0, stream>>>(
            X, NX, EW, embb, edge_w, node_w, ypre);
        gnn_head_kernel<<<BZ, 256, 0, stream>>>(ypre, fc_W, fc_b, out);
    } else {
        zero_ws_kernel<<<(BZ * DIM + 255) / 256, 256, 0, stream>>>(ypre, BZ * DIM);
        gnn_gather_f32_kernel<<<BZ * NCHUNK16, 256, 0, stream>>>(
            X, NX, EW, node_emb, edge_w, node_w, ypre);
        gnn_head_kernel<<<BZ, 256, 0, stream>>>(ypre, fc_W, fc_b, out);
    }
}